// Round 17
// baseline (153.501 us; speedup 1.0000x reference)
//
#include <hip/hip_runtime.h>

// ---------------------------------------------------------------------------
// B=1, N=10000, A=32, D=256, H=4, DH=64
// cast x->f16; tcast weights (transposed, Wq pre-scaled);
// QKV = x @ [Wq|Wkv] (m97-style f16 MFMA GEMM, global_load_lds);
// attn (branchless gathers); out = AO @ Wo + bo (same GEMM, f32 out).
// ---------------------------------------------------------------------------

typedef _Float16 f16;
typedef _Float16 f16x4 __attribute__((ext_vector_type(4)));
typedef _Float16 f16x8 __attribute__((ext_vector_type(8)));
typedef float    f32x4 __attribute__((ext_vector_type(4)));

#define TM 128
#define TN 128
#define TK 32

__device__ __forceinline__ void gload16(const f16* g, f16* l) {
    __builtin_amdgcn_global_load_lds(
        (const __attribute__((address_space(1))) unsigned int*)g,
        (__attribute__((address_space(3))) unsigned int*)l,
        16, 0, 0);
}

// f32 -> f16 cast, 8 elems/thread
__global__ __launch_bounds__(256) void cast_kernel(
    const float* __restrict__ in, f16* __restrict__ out, int n8)
{
    int i = blockIdx.x * 256 + threadIdx.x;
    if (i < n8) {
        float4 a = ((const float4*)in)[i * 2];
        float4 b = ((const float4*)in)[i * 2 + 1];
        f16x8 o = {(f16)a.x, (f16)a.y, (f16)a.z, (f16)a.w,
                   (f16)b.x, (f16)b.y, (f16)b.z, (f16)b.w};
        ((f16x8*)out)[i] = o;
    }
}

// W [K][Nn] f32 -> Wt [Nn][K] f16 (scaled). 32x32 LDS tile transpose.
__global__ __launch_bounds__(256) void tcast_kernel(
    const float* __restrict__ W, f16* __restrict__ Wt, int K, int Nn, float mul)
{
    __shared__ float s[32][33];
    const int tx = threadIdx.x & 31, ty = threadIdx.x >> 5;
    const int kb = blockIdx.y * 32, nb = blockIdx.x * 32;
#pragma unroll
    for (int r = 0; r < 4; r++)
        s[ty + r * 8][tx] = W[(size_t)(kb + ty + r * 8) * Nn + nb + tx];
    __syncthreads();
#pragma unroll
    for (int r = 0; r < 4; r++)
        Wt[(size_t)(nb + ty + r * 8) * K + kb + tx] = (f16)(s[tx][ty + r * 8] * mul);
}

// ---------------------------------------------------------------------------
// m97-style GEMM: C[M][Nn] = A[M][K] @ Bt[Nn][K]^T (+bias).
// 128x128 tile, 256 thr = 4 waves (2x2 of 64x64), BK=32, linear LDS,
// global_load_lds dwordx4 staging (2 chunks/thread/operand per K-iter),
// mfma_f32_16x16x32_f16. Fragment k-map phi(h,e)=8h+e on BOTH operands
// (any shared bijection is correct by operand-pairing symmetry).
// C/D: col=l&15, row=(l>>4)*4+j (m89-verified, shape-determined).
// ---------------------------------------------------------------------------
template <int OUT_F32>
__global__ __launch_bounds__(256) void hgemm_kernel(
    const f16* __restrict__ A, const f16* __restrict__ Bt,
    void* __restrict__ C, const float* __restrict__ bias,
    int M, int Nn, int K)
{
    __shared__ f16 As[TM * TK];   // 8 KB, linear: row*32 + k
    __shared__ f16 Bs[TN * TK];   // 8 KB
    const int tid = threadIdx.x;
    const int w  = tid >> 6, l = tid & 63;
    const int fr = l & 15,  h = l >> 4;
    const int brow = blockIdx.y * TM, bcol = blockIdx.x * TN;
    const int wr = (w >> 1) * 64, wc = (w & 1) * 64;

    // staging chunks: c covers LDS bytes [c*16, c*16+16) = tile row c>>2, slot c&3
    const int c1 = tid, c2 = tid + 256;
    const size_t aoff1 = (size_t)min(brow + (c1 >> 2), M - 1) * K + (c1 & 3) * 8;
    const size_t aoff2 = (size_t)min(brow + (c2 >> 2), M - 1) * K + (c2 & 3) * 8;
    const size_t boff1 = (size_t)(bcol + (c1 >> 2)) * K + (c1 & 3) * 8;
    const size_t boff2 = (size_t)(bcol + (c2 >> 2)) * K + (c2 & 3) * 8;

    f32x4 acc[4][4];
#pragma unroll
    for (int m = 0; m < 4; m++)
#pragma unroll
        for (int n = 0; n < 4; n++) acc[m][n] = (f32x4){0.f, 0.f, 0.f, 0.f};

    for (int kk = 0; kk < K; kk += TK) {
        gload16(A  + aoff1 + kk, &As[c1 * 8]);
        gload16(A  + aoff2 + kk, &As[c2 * 8]);
        gload16(Bt + boff1 + kk, &Bs[c1 * 8]);
        gload16(Bt + boff2 + kk, &Bs[c2 * 8]);
        __syncthreads();   // compiler drains vmcnt before s_barrier (m97 pattern)

        f16x8 af[4], bf[4];
#pragma unroll
        for (int m = 0; m < 4; m++)
            af[m] = *(const f16x8*)&As[(wr + m * 16 + fr) * TK + h * 8];
#pragma unroll
        for (int n = 0; n < 4; n++)
            bf[n] = *(const f16x8*)&Bs[(wc + n * 16 + fr) * TK + h * 8];
#pragma unroll
        for (int m = 0; m < 4; m++)
#pragma unroll
            for (int n = 0; n < 4; n++)
                acc[m][n] = __builtin_amdgcn_mfma_f32_16x16x32_f16(
                    af[m], bf[n], acc[m][n], 0, 0, 0);
        __syncthreads();
    }

#pragma unroll
    for (int m = 0; m < 4; m++) {
#pragma unroll
        for (int n = 0; n < 4; n++) {
            const int col = bcol + wc + n * 16 + fr;
#pragma unroll
            for (int j = 0; j < 4; j++) {
                const int row = brow + wr + m * 16 + h * 4 + j;
                if (row < M) {
                    if (OUT_F32)
                        ((float*)C)[(size_t)row * Nn + col] = acc[m][n][j] + bias[col];
                    else
                        ((f16*)C)[(size_t)row * Nn + col] = (f16)acc[m][n][j];
                }
            }
        }
    }
}

// ---------------------------------------------------------------------------
// Attention: block = row n, wave w = head h. 16-lane group g owns keys
// a = g mod 4 of 33 (null + 32). Branchless: K/V loads unconditional,
// mask via select. QKV row j = [Q(256, pre-scaled)|K(256)|V(256)] f16.
// (verified R8: absmax 9.8e-4, 47 us)
// ---------------------------------------------------------------------------
__global__ __launch_bounds__(256) void attn_kernel(
    const f16* __restrict__ QKV,
    const int* __restrict__ aidx, const int* __restrict__ amask,
    const float* __restrict__ nullk, const float* __restrict__ nullv,
    f16* __restrict__ out)
{
    const int n    = blockIdx.x;
    const int tid  = threadIdx.x;
    const int w    = tid >> 6;      // wave = head
    const int h    = w;
    const int lane = tid & 63;
    const int g    = lane >> 4;
    const int gl   = lane & 15;

    __shared__ int   sIdx[32];
    __shared__ int   sMsk[32];
    __shared__ float sP[4][33];

    if (tid < 32) {
        sIdx[tid] = aidx[n * 32 + tid];
        sMsk[tid] = amask[n * 32 + tid];
    }
    __syncthreads();

    f16x4 qh = *(const f16x4*)(QKV + (size_t)n * 768 + h * 64 + gl * 4);
    const float q0 = (float)qh[0], q1 = (float)qh[1], q2 = (float)qh[2], q3 = (float)qh[3];

    float sim[9];

    // round 0: a = g (group 0 = null key)
    {
        float s;
        if (g == 0) {
            float4 nk4 = ((const float4*)nullk)[h * 16 + gl];
            s = q0 * nk4.x + q1 * nk4.y + q2 * nk4.z + q3 * nk4.w;
        } else {
            int j = sIdx[g - 1];
            f16x4 kh = *(const f16x4*)(QKV + (size_t)j * 768 + 256 + h * 64 + gl * 4);
            s = q0 * (float)kh[0] + q1 * (float)kh[1] + q2 * (float)kh[2] + q3 * (float)kh[3];
        }
        s += __shfl_xor(s, 1); s += __shfl_xor(s, 2);
        s += __shfl_xor(s, 4); s += __shfl_xor(s, 8);
        bool ok = (g == 0) || (sMsk[g - 1] != 0);
        sim[0] = ok ? s : -3.0e38f;
    }

    // rounds 1..8: branchless, unconditional loads
#pragma unroll
    for (int r = 1; r < 9; r++) {
        int a  = r * 4 + g;
        int ai = min(a - 1, 31);
        int j  = sIdx[ai];
        f16x4 kh = *(const f16x4*)(QKV + (size_t)j * 768 + 256 + h * 64 + gl * 4);
        float s = q0 * (float)kh[0] + q1 * (float)kh[1] + q2 * (float)kh[2] + q3 * (float)kh[3];
        s += __shfl_xor(s, 1); s += __shfl_xor(s, 2);
        s += __shfl_xor(s, 4); s += __shfl_xor(s, 8);
        bool ok = (a < 33) && (sMsk[ai] != 0);
        sim[r] = ok ? s : -3.0e38f;
    }

    // softmax over 33
    float m = sim[0];
#pragma unroll
    for (int r = 1; r < 9; r++) m = fmaxf(m, sim[r]);
    m = fmaxf(m, __shfl_xor(m, 16));
    m = fmaxf(m, __shfl_xor(m, 32));

    float p[9]; float l = 0.0f;
#pragma unroll
    for (int r = 0; r < 9; r++) {
        p[r] = (sim[r] > -1.0e37f) ? __expf(sim[r] - m) : 0.0f;
        l += p[r];
    }
    l += __shfl_xor(l, 16);
    l += __shfl_xor(l, 32);
    const float inv = 1.0f / l;

    if (gl == 0) {
#pragma unroll
        for (int r = 0; r < 9; r++) {
            int a = r * 4 + g;
            if (a < 33) sP[w][a] = p[r] * inv;
        }
    }
    __syncthreads();

    // P @ V: lane owns output dim d = lane; all 33 loads unconditional
    float acc = sP[w][0] * nullv[h * 64 + lane];
#pragma unroll
    for (int a = 1; a <= 32; a++) {
        int j = sIdx[a - 1];
        float va = (float)QKV[(size_t)j * 768 + 512 + h * 64 + lane];
        acc += sP[w][a] * va;
    }
    out[(size_t)n * 256 + h * 64 + lane] = (f16)acc;
}

// ---------------------------------------------------------------------------
extern "C" void kernel_launch(void* const* d_in, const int* in_sizes, int n_in,
                              void* d_out, int out_size, void* d_ws, size_t ws_size,
                              hipStream_t stream)
{
    const float* x     = (const float*)d_in[0];
    const int*   aidx  = (const int*)  d_in[1];
    const int*   amask = (const int*)  d_in[2];
    const float* Wq    = (const float*)d_in[3];
    const float* Wkv   = (const float*)d_in[4];
    const float* Wo    = (const float*)d_in[5];
    const float* bo    = (const float*)d_in[6];
    const float* nk    = (const float*)d_in[7];
    const float* nv    = (const float*)d_in[8];
    float* out = (float*)d_out;

    const int N = 10000;
    f16* xh    = (f16*)d_ws;                       // N*256
    f16* Wqkvt = xh    + (size_t)N * 256;          // 768*256 (Wq^T*0.125 | Wkv^T)
    f16* Wot   = Wqkvt + 768 * 256;                // 256*256
    f16* QKV   = Wot   + 256 * 256;                // N*768
    f16* AOh   = QKV   + (size_t)N * 768;          // N*256

    dim3 blk(256);
    cast_kernel<<<dim3(N * 256 / 8 / 256 + 1), blk, 0, stream>>>(x, xh, N * 256 / 8);
    tcast_kernel<<<dim3(8,  8), blk, 0, stream>>>(Wq,  Wqkvt,             256, 256, 0.125f);
    tcast_kernel<<<dim3(16, 8), blk, 0, stream>>>(Wkv, Wqkvt + 256 * 256, 256, 512, 1.0f);
    tcast_kernel<<<dim3(8,  8), blk, 0, stream>>>(Wo,  Wot,               256, 256, 1.0f);

    const int gm = (N + TM - 1) / TM;              // 79
    hgemm_kernel<0><<<dim3(768 / TN, gm), blk, 0, stream>>>(xh,  Wqkvt, QKV, nullptr, N, 768, 256);
    attn_kernel    <<<dim3(N),            blk, 0, stream>>>(QKV, aidx, amask, nk, nv, AOh);
    hgemm_kernel<1><<<dim3(256 / TN, gm), blk, 0, stream>>>(AOh, Wot,   out, bo,      N, 256, 256);
}